// Round 4
// baseline (1006.430 us; speedup 1.0000x reference)
//
#include <hip/hip_runtime.h>
#include <hip/hip_bf16.h>

#define B_  2
#define S_  2048
#define D_  2048
#define H_  16
#define HD_ 128
#define FF_ 8192

typedef __bf16 bf16x8 __attribute__((ext_vector_type(8)));
typedef float  f32x4  __attribute__((ext_vector_type(4)));
typedef unsigned short u16;
typedef u16 u16x8 __attribute__((ext_vector_type(8)));
typedef unsigned uv4 __attribute__((ext_vector_type(4)));

__device__ __forceinline__ u16 f2bf(float f) {
    union { float f; unsigned u; } c; c.f = f;
    unsigned u = c.u;
    u += 0x7fffu + ((u >> 16) & 1u);   // RNE
    return (u16)(u >> 16);
}

__device__ __forceinline__ void gld16(void* lds, const void* g) {
    __builtin_amdgcn_global_load_lds(
        (const __attribute__((address_space(1))) unsigned int*)g,
        (__attribute__((address_space(3))) unsigned int*)lds,
        16, 0, 0);
}

// inline-asm LDS read: opaque to the waitcnt pass -> no compiler-inserted
// vmcnt(0) alias-drain against outstanding global_load_lds (rule #18).
__device__ __forceinline__ bf16x8 dsr16(const u16* p) {
    unsigned a = (unsigned)(unsigned long long)
                 (const __attribute__((address_space(3))) u16*)p;
    uv4 r;
    asm volatile("ds_read_b128 %0, %1" : "=v"(r) : "v"(a));
    union { uv4 u; bf16x8 b; } c; c.u = r;
    return c.b;
}

__device__ __forceinline__ float gelu_f(float v) {
    return 0.5f * v * (1.0f + erff(v * 0.70710678118654752f));
}

// ---------------------------------------------------------------- LayerNorm
__global__ __launch_bounds__(256)
void ln_kernel(const float* __restrict__ x, const float* __restrict__ g,
               const float* __restrict__ bb, u16* __restrict__ out)
{
    int row = blockIdx.x, tid = threadIdx.x;
    const float4* xr = (const float4*)(x + (size_t)row * D_);
    float4 a = xr[tid], c = xr[tid + 256];
    float s  = a.x + a.y + a.z + a.w + c.x + c.y + c.z + c.w;
    float s2 = a.x*a.x + a.y*a.y + a.z*a.z + a.w*a.w
             + c.x*c.x + c.y*c.y + c.z*c.z + c.w*c.w;
    #pragma unroll
    for (int off = 32; off > 0; off >>= 1) {
        s  += __shfl_down(s,  off, 64);
        s2 += __shfl_down(s2, off, 64);
    }
    __shared__ float red[16];
    __shared__ float mr[2];
    int wid = tid >> 6, lane = tid & 63;
    if (lane == 0) { red[wid] = s; red[8 + wid] = s2; }
    __syncthreads();
    if (tid == 0) {
        float ts = red[0] + red[1] + red[2] + red[3];
        float t2 = red[8] + red[9] + red[10] + red[11];
        float mu = ts * (1.0f / D_);
        float var = t2 * (1.0f / D_) - mu * mu;
        mr[0] = mu; mr[1] = rsqrtf(var + 1e-5f);
    }
    __syncthreads();
    float mu = mr[0], rstd = mr[1];
    const float4* gg = (const float4*)g;
    const float4* bv = (const float4*)bb;
    float4 g0 = gg[tid], g1 = gg[tid + 256];
    float4 b0 = bv[tid], b1 = bv[tid + 256];
    u16* orow = out + (size_t)row * D_;
    ushort4 o0, o1;
    o0.x = f2bf((a.x - mu) * rstd * g0.x + b0.x);
    o0.y = f2bf((a.y - mu) * rstd * g0.y + b0.y);
    o0.z = f2bf((a.z - mu) * rstd * g0.z + b0.z);
    o0.w = f2bf((a.w - mu) * rstd * g0.w + b0.w);
    o1.x = f2bf((c.x - mu) * rstd * g1.x + b1.x);
    o1.y = f2bf((c.y - mu) * rstd * g1.y + b1.y);
    o1.z = f2bf((c.z - mu) * rstd * g1.z + b1.z);
    o1.w = f2bf((c.w - mu) * rstd * g1.w + b1.w);
    *(ushort4*)&orow[tid * 4]         = o0;
    *(ushort4*)&orow[(tid + 256) * 4] = o1;
}

// ----------------------------------------------- transpose + fp32->bf16 cast
__global__ __launch_bounds__(256)
void tcvt_kernel(const float* __restrict__ W, u16* __restrict__ WT, int K, int N)
{
    __shared__ float t[32][33];
    int n0 = blockIdx.x << 5, k0 = blockIdx.y << 5;
    int tx = threadIdx.x & 31, ty = threadIdx.x >> 5;
    #pragma unroll
    for (int i = 0; i < 32; i += 8)
        t[ty + i][tx] = W[(size_t)(k0 + ty + i) * N + n0 + tx];
    __syncthreads();
    #pragma unroll
    for (int i = 0; i < 32; i += 8)
        WT[(size_t)(n0 + ty + i) * K + k0 + tx] = f2bf(t[tx][ty + i]);
}

// ------------------------------------------------------- GEMM bf16, 256x256
// m201-style 4-phase/K-tile schedule. 8 waves (2Mx4N), wave tile 128x64 with
// interleaved halves (rows wm*64+[0,64) of each A-half; cols wn*32+[0,32) of
// each B-half). LDS 128KB = 2 K-tile buffers x (A 2 halves + B 2 halves) of
// 128x64 bf16. Per phase: {4 or 8 ds_read_b128, stage 1 half (2 gld16), bar,
// lgkmcnt(0), 16 MFMA, bar}. Stage ring: P0:Ah1(t+1) P1:Bh1(t+1) P2:Ah0(t+2)
// P3:Bh0(t+2); every target's last reader >=2 barriers earlier. One vmcnt(2)
// per K-tile at P3 (before the pre-read of next tile's A-h0) -> 2-3 halves
// permanently in flight, never drained in-loop.
template<int EPI>
__global__ __launch_bounds__(512, 2)
void gemm256_kernel(const u16* __restrict__ A, const u16* __restrict__ BT,
                    const float* __restrict__ bias, const float* __restrict__ res,
                    void* __restrict__ outv, int M, int N, int K)
{
    __shared__ u16 lds[65536];               // 128 KB
    u16* ldsA = lds;                          // [buf][half][2 kslice][4096]
    u16* ldsB = lds + 32768;
    (void)M; (void)res;

    int tid = threadIdx.x;
    int wid = tid >> 6, lane = tid & 63;
    int wm = wid >> 2, wn = wid & 3;
    int quad = lane >> 4, l16 = lane & 15;

    int nwg = (int)gridDim.x;
    int swz = ((int)blockIdx.x & 7) * (nwg >> 3) + ((int)blockIdx.x >> 3);
    int mt = swz & 15;                        // M/256 == 16
    int nt = swz >> 4;
    int m0 = mt << 8, n0 = nt << 8;

    // staging decode (proven r1-r3): tid -> (row rS, chunk cS), XOR swizzled
    int lo3 = (tid & 7) ^ ((tid >> 3) & 7);
    int rS  = ((tid >> 3) << 1) | (lo3 >> 2);
    int cS  = (lo3 & 3) << 3;
    const u16* gA = A  + (size_t)(m0 + rS) * K + cS;
    const u16* gB = BT + (size_t)(n0 + rS) * K + cS;

    int slot   = (((l16 & 1) << 2) | quad) ^ (l16 >> 1);
    int laneRd = (l16 >> 1) * 64 + slot * 8;

    f32x4 acc[8][4] = {};
    bf16x8 aA[4][2], aB[4][2], bfr[2][2];

    auto stHalfA = [&](int bb, int h, int ko) {
        u16* d = ldsA + bb + h * 8192 + wid * 512;
        const u16* s = gA + (size_t)(h * 128) * K + ko;
        gld16(d, s);
        gld16(d + 4096, s + 32);
    };
    auto stHalfB = [&](int bb, int h, int ko) {
        u16* d = ldsB + bb + h * 8192 + wid * 512;
        const u16* s = gB + (size_t)(h * 128) * K + ko;
        gld16(d, s);
        gld16(d + 4096, s + 32);
    };

    #define MFMA16(AH, IOFF, JOFF)                                              \
        __builtin_amdgcn_s_barrier();                                           \
        asm volatile("s_waitcnt lgkmcnt(0)" ::: "memory");                      \
        __builtin_amdgcn_sched_barrier(0);                                      \
        __builtin_amdgcn_s_setprio(1);                                          \
        _Pragma("unroll")                                                       \
        for (int i = 0; i < 4; i++) {                                           \
            _Pragma("unroll")                                                   \
            for (int j = 0; j < 2; j++) {                                       \
                acc[IOFF+i][JOFF+j] = __builtin_amdgcn_mfma_f32_16x16x32_bf16(  \
                    AH[i][0], bfr[j][0], acc[IOFF+i][JOFF+j], 0, 0, 0);         \
                acc[IOFF+i][JOFF+j] = __builtin_amdgcn_mfma_f32_16x16x32_bf16(  \
                    AH[i][1], bfr[j][1], acc[IOFF+i][JOFF+j], 0, 0, 0);         \
            }                                                                   \
        }                                                                       \
        __builtin_amdgcn_sched_barrier(0);                                      \
        __builtin_amdgcn_s_setprio(0);                                          \
        __builtin_amdgcn_s_barrier();

    auto TILE = [&](int cb, int ob, bf16x8 (&aH0)[4][2], bf16x8 (&aH1)[4][2],
                    int ko1, int ko2) {
        // ---- P0: quadrant (m0,n0); read bf h0; stage Ah1(t+1)
        {
            const u16* bp = ldsB + cb + wn * 1024 + laneRd;
            #pragma unroll
            for (int f = 0; f < 2; f++)
                #pragma unroll
                for (int kk = 0; kk < 2; kk++)
                    bfr[f][kk] = dsr16(bp + f * 512 + kk * 4096);
            stHalfA(ob, 1, ko1);
            MFMA16(aH0, 0, 0)
        }
        // ---- P1: quadrant (m1,n0); read af h1; stage Bh1(t+1)
        {
            const u16* ap = ldsA + cb + 8192 + wm * 2048 + laneRd;
            #pragma unroll
            for (int f = 0; f < 4; f++)
                #pragma unroll
                for (int kk = 0; kk < 2; kk++)
                    aH1[f][kk] = dsr16(ap + f * 512 + kk * 4096);
            stHalfB(ob, 1, ko1);
            MFMA16(aH1, 4, 0)
        }
        // ---- P2: quadrant (m1,n1); read bf h1; stage Ah0(t+2)
        {
            const u16* bp = ldsB + cb + 8192 + wn * 1024 + laneRd;
            #pragma unroll
            for (int f = 0; f < 2; f++)
                #pragma unroll
                for (int kk = 0; kk < 2; kk++)
                    bfr[f][kk] = dsr16(bp + f * 512 + kk * 4096);
            stHalfA(cb, 0, ko2);
            MFMA16(aH1, 4, 2)
        }
        // ---- P3: quadrant (m0,n1); vmcnt(2); pre-read next tile's af h0
        //      into aH1 (dead; becomes next tile's aH0); stage Bh0(t+2)
        {
            asm volatile("s_waitcnt vmcnt(2)" ::: "memory");
            const u16* ap = ldsA + ob + wm * 2048 + laneRd;
            #pragma unroll
            for (int f = 0; f < 4; f++)
                #pragma unroll
                for (int kk = 0; kk < 2; kk++)
                    aH1[f][kk] = dsr16(ap + f * 512 + kk * 4096);
            stHalfB(cb, 0, ko2);
            MFMA16(aH0, 0, 2)
        }
    };

    int nkt = K >> 6;                         // even (K=2048)
    // prologue: tile0 all 4 halves + tile1 h0 halves; tile0 landed
    stHalfA(0, 0, 0);     stHalfB(0, 0, 0);
    stHalfA(0, 1, 0);     stHalfB(0, 1, 0);
    stHalfA(16384, 0, 64); stHalfB(16384, 0, 64);
    asm volatile("s_waitcnt vmcnt(4)" ::: "memory");
    __builtin_amdgcn_s_barrier();
    {   // pre-read af h0 of tile0 (completed by P0's lgkmcnt(0))
        const u16* ap = ldsA + wm * 2048 + laneRd;
        #pragma unroll
        for (int f = 0; f < 4; f++)
            #pragma unroll
            for (int kk = 0; kk < 2; kk++)
                aA[f][kk] = dsr16(ap + f * 512 + kk * 4096);
    }

    int niter = nkt >> 1;
    for (int it = 0; it < niter; ++it) {
        int t0 = it << 1;
        int a1 = t0 + 1;
        int a2 = t0 + 2; if (a2 > nkt - 1) a2 = nkt - 1;
        int a3 = t0 + 3; if (a3 > nkt - 1) a3 = nkt - 1;
        TILE(0,     16384, aA, aB, a1 << 6, a2 << 6);
        TILE(16384, 0,     aB, aA, a2 << 6, a3 << 6);
    }
    asm volatile("s_waitcnt vmcnt(0)" ::: "memory");
    __builtin_amdgcn_s_barrier();

    // ------- epilogue: LDS bounce -> full-line bf16 stores
    u16* outb = (u16*)outv;
    u16* bnc = lds + wid * 8192;              // wave-private 16 KB
    float bv[4];
    #pragma unroll
    for (int j = 0; j < 4; j++)
        bv[j] = bias[n0 + (j >> 1) * 128 + wn * 32 + (j & 1) * 16 + l16];
    #pragma unroll
    for (int h = 0; h < 2; h++) {
        #pragma unroll
        for (int ii = 0; ii < 4; ii++)
            #pragma unroll
            for (int j = 0; j < 4; j++)
                #pragma unroll
                for (int r = 0; r < 4; r++) {
                    float v = acc[h * 4 + ii][j][r] + bv[j];
                    if (EPI == 1) v = gelu_f(v);
                    int row = ii * 16 + (quad << 2) + r;
                    int pc = ((j * 2 + (l16 >> 3)) ^ (row & 7));
                    bnc[row * 64 + pc * 8 + (l16 & 7)] = f2bf(v);
                }
        #pragma unroll
        for (int p = 0; p < 8; p++) {
            int brow = p * 8 + (lane >> 3);
            int ch = lane & 7;
            int phys = ch ^ (brow & 7);
            u16x8 v8 = *(const u16x8*)&bnc[brow * 64 + phys * 8];
            int grow = m0 + h * 128 + wm * 64 + brow;
            int gcol = n0 + (ch >> 2) * 128 + wn * 32 + (ch & 3) * 8;
            *(u16x8*)&outb[(size_t)grow * N + gcol] = v8;
        }
        __builtin_amdgcn_s_barrier();   // cheap; order h0 reads before h1 writes
    }
    #undef MFMA16
}

// ------------------------------------------------------- GEMM bf16, 128x256
// round-3 core (proven): triple-buffered K-tiles, 2 phases/K-tile, 16 MFMA
// per phase, counted vmcnt(6), asm ds_read. EPI=2 only: fp32 out + residual,
// via LDS-bounce f32 epilogue (coalesced dwordx4 loads/stores).
__global__ __launch_bounds__(512, 2)
void gemm128_kernel(const u16* __restrict__ A, const u16* __restrict__ BT,
                    const float* __restrict__ bias, const float* __restrict__ res,
                    float* __restrict__ outf, int M, int N, int K)
{
    __shared__ u16 lds[73728];               // 144 KB
    u16* ldsA = lds;                          // 3 bufs x 2 kslices x 4096
    u16* ldsB = lds + 24576;                  // 3 bufs x 2 kslices x 8192
    (void)M;

    int tid = threadIdx.x;
    int wid = tid >> 6, lane = tid & 63;
    int wm = wid >> 2, wn = wid & 3;
    int quad = lane >> 4, l16 = lane & 15;

    int nwg = (int)gridDim.x;
    int swz = ((int)blockIdx.x & 7) * (nwg >> 3) + ((int)blockIdx.x >> 3);
    int mt = swz & 31;
    int nt = swz >> 5;
    int m0 = mt << 7, n0 = nt << 8;

    int lo3 = (tid & 7) ^ ((tid >> 3) & 7);
    int rS  = ((tid >> 3) << 1) | (lo3 >> 2);
    int cS  = (lo3 & 3) << 3;
    const u16* gA  = A  + (size_t)(m0 + rS) * K + cS;
    const u16* gB0 = BT + (size_t)(n0 + rS) * K + cS;
    const u16* gB1 = gB0 + (size_t)128 * K;

    int slot   = (((l16 & 1) << 2) | quad) ^ (l16 >> 1);
    int laneRd = (l16 >> 1) * 64 + slot * 8;
    int aRd = wm * 2048 + laneRd;
    int bRd = wn * 2048 + laneRd;

    f32x4 acc[4][4] = {};

    auto stA = [&](int b, int ks, int kofs) {
        gld16(ldsA + b * 8192 + ks * 4096 + wid * 512, gA + kofs);
    };
    auto stB = [&](int b, int ks, int kofs) {
        gld16(ldsB + b * 16384 + ks * 8192 + wid * 512, gB0 + kofs);
        gld16(ldsB + b * 16384 + ks * 8192 + 4096 + wid * 512, gB1 + kofs);
    };
    auto phase = [&](int bt, int ks, int stg, int kofs, bool vm) {
        stA(stg, ks, kofs);
        stB(stg, ks, kofs);
        const u16* ap = ldsA + bt * 8192 + ks * 4096 + aRd;
        const u16* bp = ldsB + bt * 16384 + ks * 8192 + bRd;
        bf16x8 af0 = dsr16(ap);
        bf16x8 af1 = dsr16(ap + 512);
        bf16x8 af2 = dsr16(ap + 1024);
        bf16x8 af3 = dsr16(ap + 1536);
        bf16x8 bf0 = dsr16(bp);
        bf16x8 bf1 = dsr16(bp + 512);
        bf16x8 bf2 = dsr16(bp + 1024);
        bf16x8 bf3 = dsr16(bp + 1536);
        __builtin_amdgcn_s_barrier();
        asm volatile("s_waitcnt lgkmcnt(0)" ::: "memory");
        __builtin_amdgcn_sched_barrier(0);
        __builtin_amdgcn_s_setprio(1);
        acc[0][0] = __builtin_amdgcn_mfma_f32_16x16x32_bf16(af0, bf0, acc[0][0], 0, 0, 0);
        acc[0][1] = __builtin_amdgcn_mfma_f32_16x16x32_bf16(af0, bf1, acc[0][1], 0, 0, 0);
        acc[0][2] = __builtin_amdgcn_mfma_f32_16x16x32_bf16(af0, bf2, acc[0][2], 0, 0, 0);
        acc[0][3] = __builtin_amdgcn_mfma_f32_16x16x32_bf16(af0, bf3, acc[0][3], 0, 0, 0);
        acc[1][0] = __builtin_amdgcn_mfma_f32_16x16x32_bf16(af1, bf0, acc[1][0], 0, 0, 0);
        acc[1][1] = __builtin_amdgcn_mfma_f32_16x16x32_bf16(af1, bf1, acc[1][1], 0, 0, 0);
        acc[1][2] = __builtin_amdgcn_mfma_f32_16x16x32_bf16(af1, bf2, acc[1][2], 0, 0, 0);
        acc[1][3] = __builtin_amdgcn_mfma_f32_16x16x32_bf16(af1, bf3, acc[1][3], 0, 0, 0);
        acc[2][0] = __builtin_amdgcn_mfma_f32_16x16x32_bf16(af2, bf0, acc[2][0], 0, 0, 0);
        acc[2][1] = __builtin_amdgcn_mfma_f32_16x16x32_bf16(af2, bf1, acc[2][1], 0, 0, 0);
        acc[2][2] = __builtin_amdgcn_mfma_f32_16x16x32_bf16(af2, bf2, acc[2][2], 0, 0, 0);
        acc[2][3] = __builtin_amdgcn_mfma_f32_16x16x32_bf16(af2, bf3, acc[2][3], 0, 0, 0);
        acc[3][0] = __builtin_amdgcn_mfma_f32_16x16x32_bf16(af3, bf0, acc[3][0], 0, 0, 0);
        acc[3][1] = __builtin_amdgcn_mfma_f32_16x16x32_bf16(af3, bf1, acc[3][1], 0, 0, 0);
        acc[3][2] = __builtin_amdgcn_mfma_f32_16x16x32_bf16(af3, bf2, acc[3][2], 0, 0, 0);
        acc[3][3] = __builtin_amdgcn_mfma_f32_16x16x32_bf16(af3, bf3, acc[3][3], 0, 0, 0);
        __builtin_amdgcn_sched_barrier(0);
        __builtin_amdgcn_s_setprio(0);
        if (vm) asm volatile("s_waitcnt vmcnt(6)" ::: "memory");
        __builtin_amdgcn_s_barrier();
    };

    int nkt = K >> 6;
    stA(0, 0, 0);  stB(0, 0, 0);
    stA(0, 1, 32); stB(0, 1, 32);
    stA(1, 0, 64); stB(1, 0, 64);
    stA(1, 1, 96); stB(1, 1, 96);
    asm volatile("s_waitcnt vmcnt(6)" ::: "memory");
    __builtin_amdgcn_s_barrier();

    int cur = 0;
    for (int t = 0; t < nkt; ++t) {
        int stg = cur - 1; if (stg < 0) stg = 2;
        int tp = t + 2; if (tp > nkt - 1) tp = nkt - 1;
        int kofs = tp << 6;
        phase(cur, 0, stg, kofs,      false);
        phase(cur, 1, stg, kofs + 32, true);
        cur = cur + 1; if (cur > 2) cur = 0;
    }
    asm volatile("s_waitcnt vmcnt(0)" ::: "memory");
    __builtin_amdgcn_s_barrier();

    // ------- epilogue: f32 LDS bounce, residual add, coalesced stores
    float* bnc = (float*)lds + wid * 4096;    // wave-private 16 KB
    int colb = n0 + wn * 64, rowb = m0 + wm * 64;
    float bv[4];
    #pragma unroll
    for (int j = 0; j < 4; j++) bv[j] = bias[colb + j * 16 + l16];
    #pragma unroll
    for (int i = 0; i < 4; i++)
        #pragma unroll
        for (int j = 0; j < 4; j++)
            #pragma unroll
            for (int r = 0; r < 4; r++) {
                int row = i * 16 + (quad << 2) + r;
                int col = j * 16 + l16;
                int c = col >> 2, lo2 = col & 3;
                int pc = c ^ (row & 7);
                bnc[row * 64 + pc * 4 + lo2] = acc[i][j][r] + bv[j];
            }
    #pragma unroll
    for (int p = 0; p < 16; p++) {
        int brow = p * 4 + (lane >> 4);
        int cl = lane & 15;
        int phys = cl ^ (brow & 7);
        f32x4 v4 = *(const f32x4*)&bnc[brow * 64 + phys * 4];
        size_t idx = (size_t)(rowb + brow) * N + colb + cl * 4;
        f32x4 r4 = *(const f32x4*)&res[idx];
        v4 += r4;
        *(f32x4*)&outf[idx] = v4;
    }
}

// ---------------------------------------------------------- flash attention
__global__ __launch_bounds__(256, 2)
void attn_kernel(const u16* __restrict__ qkv, u16* __restrict__ av)
{
    __shared__ u16 ldsK[4][64][32];          // 16 KB  [d-chunk][key][32]
    __shared__ unsigned ldsVT[128][36];      // 18 KB  [d][key-pair]
    __shared__ u16 ldsP[4][32][72];          // 18 KB  per-wave P (2 sets)
    int tid = threadIdx.x, wid = tid >> 6, lane = tid & 63;
    int quad = lane >> 4, l16 = lane & 15;
    int bh = blockIdx.y, b = bh >> 4, h = bh & 15;
    int qx = gridDim.x - 1 - blockIdx.x;     // heavy causal blocks first
    int q0 = qx << 7;
    const u16* base = qkv + (size_t)b * S_ * (3 * D_);

    bf16x8 aq[2][4];
    #pragma unroll
    for (int set = 0; set < 2; set++) {
        int qrow = q0 + set * 64 + wid * 16 + l16;
        const u16* qp = base + (size_t)qrow * (3 * D_) + h * HD_;
        #pragma unroll
        for (int kk = 0; kk < 4; kk++)
            aq[set][kk] = *(const bf16x8*)(qp + kk * 32 + quad * 8);
    }

    float m_i[2][4], l_i[2][4];
    f32x4 oacc[2][8] = {};
    #pragma unroll
    for (int s = 0; s < 2; s++)
        #pragma unroll
        for (int r = 0; r < 4; r++) { m_i[s][r] = -1e30f; l_i[s][r] = 0.f; }

    const float scale = 0.088388347648318447f;  // 1/sqrt(128)
    int ntile = 2 * qx + 2;
    for (int jt = 0; jt < ntile; jt++) {
        int j0 = jt << 6;
        #pragma unroll
        for (int j = 0; j < 4; j++) {
            int c = wid * 4 + j;
            int kk = c >> 2, kb = c & 3;
            int key = (kb << 4) + (lane >> 2);
            const u16* g = base + (size_t)(j0 + key) * (3 * D_) + D_ + h * HD_
                         + kk * 32 + ((lane & 3) << 3);
            gld16((u16*)ldsK + c * 512, g);
        }
        {
            int kp = lane & 31, dhalf = lane >> 5;
            #pragma unroll
            for (int p = 0; p < 2; p++) {
                int doff = wid * 32 + p * 16 + dhalf * 8;
                const u16* g0 = base + (size_t)(j0 + 2 * kp) * (3 * D_)
                              + 2 * D_ + h * HD_ + doff;
                u16x8 v0 = *(const u16x8*)g0;
                u16x8 v1 = *(const u16x8*)(g0 + 3 * D_);
                #pragma unroll
                for (int k = 0; k < 8; k++)
                    ldsVT[doff + k][kp] = (unsigned)v0[k] | ((unsigned)v1[k] << 16);
            }
        }
        __syncthreads();
        f32x4 sacc[2][4] = {};
        #pragma unroll
        for (int kk = 0; kk < 4; kk++)
            #pragma unroll
            for (int n = 0; n < 4; n++) {
                bf16x8 bfr = *(const bf16x8*)&ldsK[kk][(n << 4) + l16][quad << 3];
                sacc[0][n] = __builtin_amdgcn_mfma_f32_16x16x32_bf16(aq[0][kk], bfr, sacc[0][n], 0, 0, 0);
                sacc[1][n] = __builtin_amdgcn_mfma_f32_16x16x32_bf16(aq[1][kk], bfr, sacc[1][n], 0, 0, 0);
            }
        #pragma unroll
        for (int set = 0; set < 2; set++) {
            float rowmax[4] = {-1e30f, -1e30f, -1e30f, -1e30f};
            #pragma unroll
            for (int n = 0; n < 4; n++) {
                int key = j0 + (n << 4) + l16;
                #pragma unroll
                for (int r = 0; r < 4; r++) {
                    float xv = sacc[set][n][r] * scale;
                    int qr = q0 + set * 64 + wid * 16 + (quad << 2) + r;
                    if (key > qr) xv = -1e30f;
                    sacc[set][n][r] = xv;
                    rowmax[r] = fmaxf(rowmax[r], xv);
                }
            }
            #pragma unroll
            for (int off = 1; off < 16; off <<= 1)
                #pragma unroll
                for (int r = 0; r < 4; r++)
                    rowmax[r] = fmaxf(rowmax[r], __shfl_xor(rowmax[r], off, 64));
            float alpha[4], rsum[4];
            #pragma unroll
            for (int r = 0; r < 4; r++) {
                float mn = fmaxf(m_i[set][r], rowmax[r]);
                alpha[r] = __expf(m_i[set][r] - mn);
                m_i[set][r] = mn;
                rsum[r] = 0.f;
            }
            #pragma unroll
            for (int n = 0; n < 4; n++)
                #pragma unroll
                for (int r = 0; r < 4; r++) {
                    float p = __expf(sacc[set][n][r] - m_i[set][r]);
                    rsum[r] += p;
                    ldsP[wid][set * 16 + (quad << 2) + r][(n << 4) + l16] = f2bf(p);
                }
            #pragma unroll
            for (int off = 1; off < 16; off <<= 1)
                #pragma unroll
                for (int r = 0; r < 4; r++)
                    rsum[r] += __shfl_xor(rsum[r], off, 64);
            #pragma unroll
            for (int r = 0; r < 4; r++)
                l_i[set][r] = l_i[set][r] * alpha[r] + rsum[r];
            #pragma unroll
            for (int n = 0; n < 8; n++)
                #pragma unroll
                for (int r = 0; r < 4; r++)
                    oacc[set][n][r] *= alpha[r];
        }
        #pragma unroll
        for (int ks = 0; ks < 2; ks++) {
            bf16x8 pa0 = *(const bf16x8*)&ldsP[wid][l16]     [(ks << 5) + (quad << 3)];
            bf16x8 pa1 = *(const bf16x8*)&ldsP[wid][16 + l16][(ks << 5) + (quad << 3)];
            #pragma unroll
            for (int n = 0; n < 8; n++) {
                bf16x8 vb = *(const bf16x8*)&ldsVT[(n << 4) + l16][(ks << 4) + (quad << 2)];
                oacc[0][n] = __builtin_amdgcn_mfma_f32_16x16x32_bf16(pa0, vb, oacc[0][n], 0, 0, 0);
                oacc[1][n] = __builtin_amdgcn_mfma_f32_16x16x32_bf16(pa1, vb, oacc[1][n], 0, 0, 0);
            }
        }
        __syncthreads();
    }
    #pragma unroll
    for (int set = 0; set < 2; set++)
        #pragma unroll
        for (int r = 0; r < 4; r++) {
            float inv = 1.0f / l_i[set][r];
            int qr = q0 + set * 64 + wid * 16 + (quad << 2) + r;
            u16* op = av + (size_t)(b * S_ + qr) * D_ + h * HD_;
            #pragma unroll
            for (int n = 0; n < 8; n++)
                op[(n << 4) + l16] = f2bf(oacc[set][n][r] * inv);
        }
}

// ------------------------------------------------------------------- launch
extern "C" void kernel_launch(void* const* d_in, const int* in_sizes, int n_in,
                              void* d_out, int out_size, void* d_ws, size_t ws_size,
                              hipStream_t stream)
{
    const float* x     = (const float*)d_in[0];
    const float* ln1_g = (const float*)d_in[1];
    const float* ln1_b = (const float*)d_in[2];
    const float* qkv_w = (const float*)d_in[3];
    const float* qkv_b = (const float*)d_in[4];
    const float* out_w = (const float*)d_in[5];
    const float* out_b = (const float*)d_in[6];
    const float* ln2_g = (const float*)d_in[7];
    const float* ln2_b = (const float*)d_in[8];
    const float* w1    = (const float*)d_in[9];
    const float* b1    = (const float*)d_in[10];
    const float* w2    = (const float*)d_in[11];
    const float* b2    = (const float*)d_in[12];
    float* out = (float*)d_out;

    char* ws  = (char*)d_ws;
    u16* wT   = (u16*)ws;                        // 32 MiB: transposed bf16 weights
    u16* hbuf = (u16*)(ws + (32u << 20));        // 16 MiB: ln1-out / av / ln2-out
    u16* big  = (u16*)(ws + (48u << 20));        // 64 MiB: qkv, then ffn act
    u16* qkvb = big;
    u16* ffb  = big;

    dim3 blk(256);
    dim3 gblk(512);

    ln_kernel<<<dim3(B_ * S_), blk, 0, stream>>>(x, ln1_g, ln1_b, hbuf);
    tcvt_kernel<<<dim3(6144 / 32, 2048 / 32), blk, 0, stream>>>(qkv_w, wT, 2048, 6144);
    gemm256_kernel<0><<<dim3((6144 / 256) * (4096 / 256)), gblk, 0, stream>>>(
        hbuf, wT, qkv_b, nullptr, (void*)qkvb, 4096, 6144, 2048);
    attn_kernel<<<dim3(S_ / 128, B_ * H_), blk, 0, stream>>>(qkvb, hbuf);
    tcvt_kernel<<<dim3(2048 / 32, 2048 / 32), blk, 0, stream>>>(out_w, wT, 2048, 2048);
    gemm128_kernel<<<dim3((2048 / 256) * (4096 / 128)), gblk, 0, stream>>>(
        hbuf, wT, out_b, x, out, 4096, 2048, 2048);
    ln_kernel<<<dim3(B_ * S_), blk, 0, stream>>>(out, ln2_g, ln2_b, hbuf);
    tcvt_kernel<<<dim3(8192 / 32, 2048 / 32), blk, 0, stream>>>(w1, wT, 2048, 8192);
    gemm256_kernel<1><<<dim3((8192 / 256) * (4096 / 256)), gblk, 0, stream>>>(
        hbuf, wT, b1, nullptr, (void*)ffb, 4096, 8192, 2048);
    tcvt_kernel<<<dim3(2048 / 32, 8192 / 32), blk, 0, stream>>>(w2, wT, 8192, 2048);
    gemm128_kernel<<<dim3((2048 / 256) * (4096 / 128)), gblk, 0, stream>>>(
        ffb, wT, b2, out, out, 4096, 2048, 8192);
}